// Round 1
// baseline (4201.605 us; speedup 1.0000x reference)
//
#include <hip/hip_runtime.h>
#include <cstddef>
#include <cstdint>

#define NN 50000
#define EE 800000

constexpr float BN_EPS   = 1e-5f;
constexpr float NEGSLOPE = 0.2f;

// ---------------- CSR build: group edges by (dst*4 + class) ----------------
__global__ void count_edges_k(const int* __restrict__ ei, const int* __restrict__ cls,
                              int* __restrict__ counts) {
  int e = blockIdx.x * 256 + threadIdx.x;
  if (e >= EE) return;
  int dst = ei[EE + e];
  int c   = cls[e];
  atomicAdd(&counts[dst * 4 + c], 1);
}

__global__ void scan_k(const int* __restrict__ counts, int* __restrict__ rs, int n) {
  __shared__ int tmp[1024];
  __shared__ int carry;
  int tid = threadIdx.x;
  if (tid == 0) { carry = 0; rs[0] = 0; }
  __syncthreads();
  for (int base = 0; base < n; base += 1024) {
    int i = base + tid;
    int v = (i < n) ? counts[i] : 0;
    tmp[tid] = v;
    __syncthreads();
    for (int off = 1; off < 1024; off <<= 1) {
      int t = (tid >= off) ? tmp[tid - off] : 0;
      __syncthreads();
      tmp[tid] += t;
      __syncthreads();
    }
    if (i < n) rs[i + 1] = carry + tmp[tid];
    __syncthreads();
    if (tid == 1023) carry += tmp[1023];
    __syncthreads();
  }
}

__global__ void fill_edges_k(const int* __restrict__ ei, const int* __restrict__ cls,
                             const int* __restrict__ rs, int* __restrict__ cursor,
                             int* __restrict__ ssrc) {
  int e = blockIdx.x * 256 + threadIdx.x;
  if (e >= EE) return;
  int dst = ei[EE + e];
  int c   = cls[e];
  int bin = dst * 4 + c;
  int pos = rs[bin] + atomicAdd(&cursor[bin], 1);
  ssrc[pos] = ei[e];  // src node
}

// ---------------- BatchNorm ----------------
__global__ void bn_stats_k(const float* __restrict__ x, float* __restrict__ sums,
                           int din, int total) {
  __shared__ float ls[512];
  int t = threadIdx.x;
  for (int i = t; i < 2 * din; i += 256) ls[i] = 0.f;
  __syncthreads();
  int c = (blockIdx.x * 256 + t) % din;  // din | 256, grid stride multiple of din
  float s = 0.f, ss = 0.f;
  for (int idx = blockIdx.x * 256 + t; idx < total; idx += gridDim.x * 256) {
    float v = x[idx];
    s += v; ss += v * v;
  }
  atomicAdd(&ls[c], s);
  atomicAdd(&ls[din + c], ss);
  __syncthreads();
  for (int i = t; i < 2 * din; i += 256) atomicAdd(&sums[i], ls[i]);
}

__global__ void bn_finalize_k(const float* __restrict__ sums, const float* __restrict__ g,
                              const float* __restrict__ b, float* __restrict__ scale,
                              float* __restrict__ shift, int din,
                              const float* __restrict__ skb, const float* __restrict__ cb,
                              float* __restrict__ skbe, int hd) {
  int i = threadIdx.x;
  if (i < din) {
    float m  = sums[i] / (float)NN;
    float v  = sums[din + i] / (float)NN - m * m;
    float r  = rsqrtf(v + BN_EPS);
    float sc = r * g[i];
    scale[i] = sc;
    shift[i] = b[i] - m * sc;
  }
  if (i < hd) {
    float acc = skb[i];
    #pragma unroll
    for (int j = 0; j < 4; j++) acc += cb[j * hd + i];
    skbe[i] = acc;
  }
}

__global__ void bn_apply_k(const float* __restrict__ x, float* __restrict__ xn,
                           const float* __restrict__ scale, const float* __restrict__ shift,
                           int dmask, int total) {
  for (int i = blockIdx.x * 256 + threadIdx.x; i < total; i += gridDim.x * 256) {
    int c = i & dmask;
    xn[i] = x[i] * scale[c] + shift[c];
  }
}

// ---------------- f32 GEMM: C[M,Nc] = A[M,K] @ B[K,Nc] (+bias) ----------------
__global__ __launch_bounds__(256) void gemm_f32_k(const float* __restrict__ A,
                                                  const float* __restrict__ B,
                                                  const float* __restrict__ bias,
                                                  float* __restrict__ C,
                                                  int M, int K, int Nc) {
  __shared__ float As[16][68];
  __shared__ float Bs[16][68];
  int tid  = threadIdx.x;
  int row0 = blockIdx.y * 64;
  int col0 = blockIdx.x * 64;
  int tx = tid & 15, ty = tid >> 4;
  float acc[4][4] = {};
  bool mfull = (row0 + 64 <= M);
  bool nfull = (col0 + 64 <= Nc);
  int am = tid >> 2, ak = (tid & 3) * 4;
  int bk = tid >> 4, bn = (tid & 15) * 4;
  for (int k0 = 0; k0 < K; k0 += 16) {
    if (mfull || (row0 + am) < M) {
      const float4 v = *(const float4*)(A + (size_t)(row0 + am) * K + k0 + ak);
      As[ak + 0][am] = v.x; As[ak + 1][am] = v.y; As[ak + 2][am] = v.z; As[ak + 3][am] = v.w;
    } else {
      As[ak + 0][am] = 0.f; As[ak + 1][am] = 0.f; As[ak + 2][am] = 0.f; As[ak + 3][am] = 0.f;
    }
    if (nfull) {
      const float4 v = *(const float4*)(B + (size_t)(k0 + bk) * Nc + col0 + bn);
      Bs[bk][bn + 0] = v.x; Bs[bk][bn + 1] = v.y; Bs[bk][bn + 2] = v.z; Bs[bk][bn + 3] = v.w;
    } else {
      #pragma unroll
      for (int i = 0; i < 4; i++) {
        int c = col0 + bn + i;
        Bs[bk][bn + i] = (c < Nc) ? B[(size_t)(k0 + bk) * Nc + c] : 0.f;
      }
    }
    __syncthreads();
    #pragma unroll
    for (int k = 0; k < 16; k++) {
      float a[4], bb[4];
      #pragma unroll
      for (int i = 0; i < 4; i++) a[i] = As[k][ty * 4 + i];
      #pragma unroll
      for (int i = 0; i < 4; i++) bb[i] = Bs[k][tx * 4 + i];
      #pragma unroll
      for (int i = 0; i < 4; i++)
        #pragma unroll
        for (int j = 0; j < 4; j++) acc[i][j] += a[i] * bb[j];
    }
    __syncthreads();
  }
  #pragma unroll
  for (int i = 0; i < 4; i++) {
    int r = row0 + ty * 4 + i;
    if (r < M) {
      #pragma unroll
      for (int j = 0; j < 4; j++) {
        int c = col0 + tx * 4 + j;
        if (c < Nc) {
          float v = acc[i][j];
          if (bias) v += bias[c];
          C[(size_t)r * Nc + c] = v;
        }
      }
    }
  }
}

// ---------------- attention scores es/ed per node ----------------
template <int H, int D>
__global__ void attn_scores_k(const float* __restrict__ hfeat,
                              const float* __restrict__ asrc,
                              const float* __restrict__ adst,
                              float* __restrict__ es, float* __restrict__ ed) {
  int node = blockIdx.x * 4 + (threadIdx.x >> 6);
  int lane = threadIdx.x & 63;
  if (node >= NN) return;
  const float* hrow = hfeat + (size_t)node * H * D;
  #pragma unroll
  for (int h = 0; h < H; h++) {
    float ps = 0.f, pd = 0.f;
    for (int d = lane; d < D; d += 64) {
      float v = hrow[h * D + d];
      ps += v * asrc[h * D + d];
      pd += v * adst[h * D + d];
    }
    #pragma unroll
    for (int off = 32; off > 0; off >>= 1) {
      ps += __shfl_down(ps, off);
      pd += __shfl_down(pd, off);
    }
    if (lane == 0) {
      es[(size_t)node * H + h] = ps;
      ed[(size_t)node * H + h] = pd;
    }
  }
}

__device__ inline float sel4(const float v[4], int h) {
  float r = v[0];
  r = (h == 1) ? v[1] : r;
  r = (h == 2) ? v[2] : r;
  r = (h == 3) ? v[3] : r;
  return r;
}

__device__ inline float leaky(float e) { return e >= 0.f ? e : NEGSLOPE * e; }

// ---------------- per-dst softmax + aggregate, one wave per node ----------------
template <int H, int D>
__global__ void gat_aggregate_k(const float* __restrict__ hfeat,
                                const float* __restrict__ es,
                                const float* __restrict__ ed,
                                const int* __restrict__ rs,
                                const int* __restrict__ ssrc,
                                float* __restrict__ x0, int cls) {
  constexpr int HD = H * D;
  int node = blockIdx.x;
  int lane = threadIdx.x;
  int beg = rs[node * 4 + cls];
  int end = rs[node * 4 + cls + 1];
  if (beg == end) return;  // empty group: conv contributes 0 (bias already folded)

  float edv[H];
  #pragma unroll
  for (int h = 0; h < H; h++) edv[h] = ed[(size_t)node * H + h];

  // pass 1: per-(class,head) max over this node's in-edges
  float em[H];
  #pragma unroll
  for (int h = 0; h < H; h++) em[h] = -1e30f;
  for (int i = beg + lane; i < end; i += 64) {
    int s = ssrc[i];
    #pragma unroll
    for (int h = 0; h < H; h++) {
      float e = leaky(es[(size_t)s * H + h] + edv[h]);
      em[h] = fmaxf(em[h], e);
    }
  }
  #pragma unroll
  for (int h = 0; h < H; h++)
    #pragma unroll
    for (int off = 32; off > 0; off >>= 1)
      em[h] = fmaxf(em[h], __shfl_xor(em[h], off));

  // pass 2: denominator
  float den[H];
  #pragma unroll
  for (int h = 0; h < H; h++) den[h] = 0.f;
  for (int i = beg + lane; i < end; i += 64) {
    int s = ssrc[i];
    #pragma unroll
    for (int h = 0; h < H; h++) {
      float e = leaky(es[(size_t)s * H + h] + edv[h]);
      den[h] += __expf(e - em[h]);
    }
  }
  #pragma unroll
  for (int h = 0; h < H; h++) {
    #pragma unroll
    for (int off = 32; off > 0; off >>= 1) den[h] += __shfl_xor(den[h], off);
    den[h] = 1.f / den[h];
  }

  // pass 3: weighted feature sum
  if constexpr (H == 4 && D == 64) {
    int h = lane >> 4;  // dims lane*4..lane*4+3 all in head lane/16
    float emh = sel4(em, h), dnh = sel4(den, h), edh = sel4(edv, h);
    float4 acc = make_float4(0.f, 0.f, 0.f, 0.f);
    for (int i = beg; i < end; i++) {
      int s = ssrc[i];
      float e = leaky(es[(size_t)s * 4 + h] + edh);
      float a = __expf(e - emh) * dnh;
      const float4 f = *(const float4*)(hfeat + (size_t)s * HD + lane * 4);
      acc.x += a * f.x; acc.y += a * f.y; acc.z += a * f.z; acc.w += a * f.w;
    }
    float4* xp = (float4*)(x0 + (size_t)node * HD + lane * 4);
    float4 cur = *xp;
    cur.x += acc.x; cur.y += acc.y; cur.z += acc.z; cur.w += acc.w;
    *xp = cur;
  } else {
    // H==1, tiny D: lane-parallel over edges
    float acc[D];
    #pragma unroll
    for (int d = 0; d < D; d++) acc[d] = 0.f;
    for (int i = beg + lane; i < end; i += 64) {
      int s = ssrc[i];
      float e = leaky(es[s] + edv[0]);
      float a = __expf(e - em[0]) * den[0];
      #pragma unroll
      for (int d = 0; d < D; d++) acc[d] += a * hfeat[(size_t)s * D + d];
    }
    #pragma unroll
    for (int d = 0; d < D; d++)
      #pragma unroll
      for (int off = 32; off > 0; off >>= 1) acc[d] += __shfl_xor(acc[d], off);
    if (lane == 0) {
      #pragma unroll
      for (int d = 0; d < D; d++) x0[(size_t)node * D + d] += acc[d];
    }
  }
}

__global__ void relu_k(const float* __restrict__ in, float* __restrict__ out, int n) {
  for (int i = blockIdx.x * 256 + threadIdx.x; i < n; i += gridDim.x * 256)
    out[i] = fmaxf(in[i], 0.f);
}

// ---------------- launch ----------------
extern "C" void kernel_launch(void* const* d_in, const int* in_sizes, int n_in,
                              void* d_out, int out_size, void* d_ws, size_t ws_size,
                              hipStream_t stream) {
  (void)in_sizes; (void)n_in; (void)out_size; (void)ws_size;
  const float* x_in = (const float*)d_in[0];
  const int* ei  = (const int*)d_in[1];
  const int* cls = (const int*)d_in[2];
  const float *W[3], *Asr[3], *Adr[3], *cb[3], *skW[3], *skb[3], *bng[3], *bnb[3];
  for (int i = 0; i < 3; i++) {
    int b = 3 + 8 * i;
    W[i]   = (const float*)d_in[b + 0];
    Asr[i] = (const float*)d_in[b + 1];
    Adr[i] = (const float*)d_in[b + 2];
    cb[i]  = (const float*)d_in[b + 3];
    skW[i] = (const float*)d_in[b + 4];
    skb[i] = (const float*)d_in[b + 5];
    bng[i] = (const float*)d_in[b + 6];
    bnb[i] = (const float*)d_in[b + 7];
  }
  float* out = (float*)d_out;

  char* w = (char*)d_ws;
  auto alloc = [&](size_t bytes) {
    char* p = w;
    w += (bytes + 255) & ~(size_t)255;
    return p;
  };
  float* xa    = (float*)alloc((size_t)NN * 256 * 4);  // normalized x (stride din)
  float* x0    = (float*)alloc((size_t)NN * 256 * 4);  // accumulator
  float* hfeat = (float*)alloc((size_t)NN * 256 * 4);  // per-class projection
  float* esb   = (float*)alloc((size_t)NN * 4 * 4);
  float* edb   = (float*)alloc((size_t)NN * 4 * 4);
  float* stats = (float*)alloc(512 * 4);
  float* scale = (float*)alloc(256 * 4);
  float* shift = (float*)alloc(256 * 4);
  float* skbe  = (float*)alloc(256 * 4);
  int* counts  = (int*)alloc((size_t)NN * 4 * 4);
  int* rs      = (int*)alloc(((size_t)NN * 4 + 1) * 4);
  int* cursor  = (int*)alloc((size_t)NN * 4 * 4);
  int* ssrc    = (int*)alloc((size_t)EE * 4);

  // CSR by (dst, class) — once per call
  hipMemsetAsync(counts, 0, (size_t)NN * 4 * 4, stream);
  hipMemsetAsync(cursor, 0, (size_t)NN * 4 * 4, stream);
  count_edges_k<<<(EE + 255) / 256, 256, 0, stream>>>(ei, cls, counts);
  scan_k<<<1, 1024, 0, stream>>>(counts, rs, NN * 4);
  fill_edges_k<<<(EE + 255) / 256, 256, 0, stream>>>(ei, cls, rs, cursor, ssrc);

  const int dins[3] = {64, 256, 256};
  const int HDs[3]  = {256, 256, 2};
  const float* lin = x_in;
  for (int L = 0; L < 3; L++) {
    int din = dins[L], HD = HDs[L];
    int total = NN * din;
    hipMemsetAsync(stats, 0, 512 * 4, stream);
    bn_stats_k<<<512, 256, 0, stream>>>(lin, stats, din, total);
    bn_finalize_k<<<1, 256, 0, stream>>>(stats, bng[L], bnb[L], scale, shift, din,
                                         skb[L], cb[L], skbe, HD);
    bn_apply_k<<<2048, 256, 0, stream>>>(lin, xa, scale, shift, din - 1, total);

    dim3 gg((HD + 63) / 64, (NN + 63) / 64);
    gemm_f32_k<<<gg, 256, 0, stream>>>(xa, skW[L], skbe, x0, NN, din, HD);
    for (int j = 0; j < 4; j++) {
      gemm_f32_k<<<gg, 256, 0, stream>>>(xa, W[L] + (size_t)j * din * HD, nullptr,
                                         hfeat, NN, din, HD);
      if (L < 2) {
        attn_scores_k<4, 64><<<NN / 4, 256, 0, stream>>>(hfeat, Asr[L] + j * 256,
                                                         Adr[L] + j * 256, esb, edb);
        gat_aggregate_k<4, 64><<<NN, 64, 0, stream>>>(hfeat, esb, edb, rs, ssrc, x0, j);
      } else {
        attn_scores_k<1, 2><<<NN / 4, 256, 0, stream>>>(hfeat, Asr[L] + j * 2,
                                                        Adr[L] + j * 2, esb, edb);
        gat_aggregate_k<1, 2><<<NN, 64, 0, stream>>>(hfeat, esb, edb, rs, ssrc, x0, j);
      }
    }
    float* dst = (L == 2) ? out : xa;
    relu_k<<<2048, 256, 0, stream>>>(x0, dst, NN * HD);
    lin = xa;
  }
}

// Round 2
// 3296.635 us; speedup vs baseline: 1.2745x; 1.2745x over previous
//
#include <hip/hip_runtime.h>
#include <cstddef>
#include <cstdint>

#define NN 50000
#define EE 800000

constexpr float BN_EPS   = 1e-5f;
constexpr float NEGSLOPE = 0.2f;

typedef short s16x8 __attribute__((ext_vector_type(8)));
typedef float f32x4 __attribute__((ext_vector_type(4)));
typedef unsigned short u16x4 __attribute__((ext_vector_type(4)));

__device__ __forceinline__ unsigned short f2bf(float f) {
  unsigned int u = __float_as_uint(f);
  unsigned int r = (u + 0x7fffu + ((u >> 16) & 1u)) >> 16;
  return (unsigned short)r;
}
__device__ __forceinline__ float bf2f(unsigned short u) {
  return __uint_as_float(((unsigned int)u) << 16);
}
__device__ __forceinline__ float leaky(float e) { return e >= 0.f ? e : NEGSLOPE * e; }
__device__ __forceinline__ float sel4(const float v[4], int h) {
  float r = v[0];
  r = (h == 1) ? v[1] : r;
  r = (h == 2) ? v[2] : r;
  r = (h == 3) ? v[3] : r;
  return r;
}
__device__ __forceinline__ void gl_lds16(const unsigned short* g, unsigned short* l) {
  __builtin_amdgcn_global_load_lds(
      (const __attribute__((address_space(1))) unsigned int*)(g),
      (__attribute__((address_space(3))) unsigned int*)(l), 16, 0, 0);
}

// ---------------- CSR build: group edges by (dst*4 + class) ----------------
__global__ void count_edges_k(const int* __restrict__ ei, const int* __restrict__ cls,
                              int* __restrict__ counts) {
  int e = blockIdx.x * 256 + threadIdx.x;
  if (e >= EE) return;
  int dst = ei[EE + e];
  int c   = cls[e];
  atomicAdd(&counts[dst * 4 + c], 1);
}

// hierarchical scan over n=200000: 196 blocks x 1024 elems
__global__ void scan_local_k(const int* __restrict__ counts, int* __restrict__ rs,
                             int* __restrict__ bsum, int n) {
  __shared__ int sh[256];
  int b = blockIdx.x, t = threadIdx.x;
  int base = b * 1024;
  int v[4];
  #pragma unroll
  for (int q = 0; q < 4; q++) {
    int i = base + t * 4 + q;
    v[q] = (i < n) ? counts[i] : 0;
  }
  v[1] += v[0]; v[2] += v[1]; v[3] += v[2];
  sh[t] = v[3];
  __syncthreads();
  for (int off = 1; off < 256; off <<= 1) {
    int x = (t >= off) ? sh[t - off] : 0;
    __syncthreads();
    sh[t] += x;
    __syncthreads();
  }
  int prev = (t > 0) ? sh[t - 1] : 0;
  #pragma unroll
  for (int q = 0; q < 4; q++) {
    int i = base + t * 4 + q;
    if (i < n) rs[i + 1] = prev + v[q];
  }
  if (t == 255) bsum[b] = sh[255];
}

__global__ void scan_bsum_k(int* __restrict__ bsum, int nb) {
  __shared__ int sh[256];
  int t = threadIdx.x;
  sh[t] = (t < nb) ? bsum[t] : 0;
  __syncthreads();
  for (int off = 1; off < 256; off <<= 1) {
    int x = (t >= off) ? sh[t - off] : 0;
    __syncthreads();
    sh[t] += x;
    __syncthreads();
  }
  if (t < nb) bsum[t] = (t > 0) ? sh[t - 1] : 0;
}

__global__ void scan_add_k(int* __restrict__ rs, const int* __restrict__ bsum, int n) {
  int b = blockIdx.x, t = threadIdx.x;
  int off = bsum[b];
  #pragma unroll
  for (int q = 0; q < 4; q++) {
    int i = b * 1024 + t * 4 + q;
    if (i < n) rs[i + 1] += off;
  }
  if (b == 0 && t == 0) rs[0] = 0;
}

__global__ void fill_edges_k(const int* __restrict__ ei, const int* __restrict__ cls,
                             const int* __restrict__ rs, int* __restrict__ cursor,
                             int* __restrict__ ssrc) {
  int e = blockIdx.x * 256 + threadIdx.x;
  if (e >= EE) return;
  int dst = ei[EE + e];
  int c   = cls[e];
  int bin = dst * 4 + c;
  int pos = rs[bin] + atomicAdd(&cursor[bin], 1);
  ssrc[pos] = ei[e];
}

// ---------------- BatchNorm ----------------
__global__ void bn_stats_k(const float* __restrict__ x, float* __restrict__ sums,
                           int din, int total) {
  __shared__ float ls[512];
  int t = threadIdx.x;
  for (int i = t; i < 2 * din; i += 256) ls[i] = 0.f;
  __syncthreads();
  int c = (blockIdx.x * 256 + t) % din;
  float s = 0.f, ss = 0.f;
  for (int idx = blockIdx.x * 256 + t; idx < total; idx += gridDim.x * 256) {
    float v = x[idx];
    s += v; ss += v * v;
  }
  atomicAdd(&ls[c], s);
  atomicAdd(&ls[din + c], ss);
  __syncthreads();
  for (int i = t; i < 2 * din; i += 256) atomicAdd(&sums[i], ls[i]);
}

__global__ void bn_finalize_k(const float* __restrict__ sums, const float* __restrict__ g,
                              const float* __restrict__ b, float* __restrict__ scale,
                              float* __restrict__ shift, int din,
                              const float* __restrict__ skb, const float* __restrict__ cb,
                              float* __restrict__ skbe, int hd) {
  int i = threadIdx.x;
  if (i < din) {
    float m  = sums[i] / (float)NN;
    float v  = sums[din + i] / (float)NN - m * m;
    float r  = rsqrtf(v + BN_EPS);
    float sc = r * g[i];
    scale[i] = sc;
    shift[i] = b[i] - m * sc;
  }
  if (i < hd) {
    float acc = skb[i];
    #pragma unroll
    for (int j = 0; j < 4; j++) acc += cb[j * hd + i];
    skbe[i] = acc;
  }
}

__global__ void bn_apply_bf16_k(const float* __restrict__ x, unsigned short* __restrict__ xn,
                                const float* __restrict__ scale, const float* __restrict__ shift,
                                int dmask, int total) {
  for (int i = blockIdx.x * 256 + threadIdx.x; i < total; i += gridDim.x * 256) {
    int c = i & dmask;
    xn[i] = f2bf(x[i] * scale[c] + shift[c]);
  }
}

// ---------------- weight convert+transpose to bf16 (all layers 0/1 at once) ----------------
__global__ void conv_weights_k(const float* __restrict__ skW0, const float* __restrict__ W0,
                               const float* __restrict__ skW1, const float* __restrict__ W1,
                               unsigned short* __restrict__ wt) {
  int o = blockIdx.x * 256 + threadIdx.x;
  if (o >= 409600) return;
  float v;
  if (o < 16384) {                       // skW0^T [256][64]
    int n = o >> 6, k = o & 63;
    v = skW0[k * 256 + n];
  } else if (o < 81920) {                // W0^T [4][256][64]
    int w = o - 16384; int j = w >> 14; w &= 16383;
    int n = w >> 6, k = w & 63;
    v = W0[j * 16384 + k * 256 + n];
  } else if (o < 147456) {               // skW1^T [256][256]
    int w = o - 81920;
    int n = w >> 8, k = w & 255;
    v = skW1[k * 256 + n];
  } else {                               // W1^T [4][256][256]
    int w = o - 147456; int j = w >> 16; w &= 65535;
    int n = w >> 8, k = w & 255;
    v = W1[j * 65536 + k * 256 + n];
  }
  wt[o] = f2bf(v);
}

// ---------------- bf16 MFMA GEMM: C[M,N] = A[M,K] * Bt[N,K]^T ----------------
// 128x128 tile, BK=32, 4 waves (2x2 of 64x64), m97-style global_load_lds staging.
__global__ __launch_bounds__(256) void gemm_bf16_k(
    const unsigned short* __restrict__ A,   // [M,K] bf16
    const unsigned short* __restrict__ Bt,  // [N,K] bf16
    const float* __restrict__ bias,         // [N] or null
    float* __restrict__ Cf,                 // f32 out (or null)
    unsigned short* __restrict__ Cb,        // bf16 out (or null)
    int M, int K, int N) {
  __shared__ unsigned short As[128 * 32];
  __shared__ unsigned short Bs[128 * 32];
  int tid  = threadIdx.x;
  int lane = tid & 63;
  int w    = tid >> 6;
  int lm = lane & 15, lq = lane >> 4;
  int row0 = blockIdx.y * 128, col0 = blockIdx.x * 128;
  int wr = (w >> 1) * 64, wc = (w & 1) * 64;
  f32x4 acc[4][4];
  #pragma unroll
  for (int i = 0; i < 4; i++)
    #pragma unroll
    for (int j = 0; j < 4; j++) acc[i][j] = {0.f, 0.f, 0.f, 0.f};
  int ldsbase = (tid & ~63) * 16;  // byte offset of this wave's lane-0 chunk (r=0)

  for (int k0 = 0; k0 < K; k0 += 32) {
    #pragma unroll
    for (int r = 0; r < 2; r++) {
      int ia = r * 256 + tid;                 // 16B chunk index in tile
      int arow = row0 + (ia >> 2);
      if (arow >= M) arow = M - 1;            // clamp; those C rows never stored
      const unsigned short* ga = A + (size_t)arow * K + k0 + (ia & 3) * 8;
      gl_lds16(ga, (unsigned short*)((char*)As + r * 4096 + ldsbase));
      int bcol = col0 + (ia >> 2);            // N is always a multiple of 128 here
      const unsigned short* gb = Bt + (size_t)bcol * K + k0 + (ia & 3) * 8;
      gl_lds16(gb, (unsigned short*)((char*)Bs + r * 4096 + ldsbase));
    }
    __syncthreads();
    s16x8 af[4], bfr[4];
    #pragma unroll
    for (int i = 0; i < 4; i++)
      af[i] = *(const s16x8*)&As[(wr + i * 16 + lm) * 32 + lq * 8];
    #pragma unroll
    for (int j = 0; j < 4; j++)
      bfr[j] = *(const s16x8*)&Bs[(wc + j * 16 + lm) * 32 + lq * 8];
    #pragma unroll
    for (int i = 0; i < 4; i++)
      #pragma unroll
      for (int j = 0; j < 4; j++)
        acc[i][j] = __builtin_amdgcn_mfma_f32_16x16x32_bf16(af[i], bfr[j], acc[i][j], 0, 0, 0);
    __syncthreads();
  }

  #pragma unroll
  for (int i = 0; i < 4; i++) {
    #pragma unroll
    for (int j = 0; j < 4; j++) {
      int c = col0 + wc + j * 16 + lm;
      #pragma unroll
      for (int rg = 0; rg < 4; rg++) {
        int r = row0 + wr + i * 16 + lq * 4 + rg;
        if (r < M) {
          float v = acc[i][j][rg];
          if (Cf) {
            if (bias) v += bias[c];
            Cf[(size_t)r * N + c] = v;
          } else {
            Cb[(size_t)r * N + c] = f2bf(v);
          }
        }
      }
    }
  }
}

// ---------------- attention scores (H=4, D=64, bf16 hfeat) ----------------
__global__ void attn_scores4_k(const unsigned short* __restrict__ hfeat,
                               const float* __restrict__ asrc,
                               const float* __restrict__ adst,
                               float* __restrict__ es, float* __restrict__ ed) {
  int node = blockIdx.x * 4 + (threadIdx.x >> 6);
  int lane = threadIdx.x & 63;
  if (node >= NN) return;
  const unsigned short* hrow = hfeat + (size_t)node * 256;
  #pragma unroll
  for (int h = 0; h < 4; h++) {
    float v  = bf2f(hrow[h * 64 + lane]);
    float ps = v * asrc[h * 64 + lane];
    float pd = v * adst[h * 64 + lane];
    #pragma unroll
    for (int off = 32; off > 0; off >>= 1) {
      ps += __shfl_down(ps, off);
      pd += __shfl_down(pd, off);
    }
    if (lane == 0) {
      es[(size_t)node * 4 + h] = ps;
      ed[(size_t)node * 4 + h] = pd;
    }
  }
}

// ---------------- aggregate H=4, D=64 (bf16 hfeat) ----------------
__global__ void gat_agg4_k(const unsigned short* __restrict__ hfeat,
                           const float* __restrict__ es, const float* __restrict__ ed,
                           const int* __restrict__ rs, const int* __restrict__ ssrc,
                           float* __restrict__ x0, int cls) {
  int node = blockIdx.x;
  int lane = threadIdx.x;
  int beg = rs[node * 4 + cls];
  int end = rs[node * 4 + cls + 1];
  if (beg == end) return;

  float edv[4];
  #pragma unroll
  for (int h = 0; h < 4; h++) edv[h] = ed[(size_t)node * 4 + h];

  float em[4] = {-1e30f, -1e30f, -1e30f, -1e30f};
  for (int i = beg + lane; i < end; i += 64) {
    int s = ssrc[i];
    #pragma unroll
    for (int h = 0; h < 4; h++)
      em[h] = fmaxf(em[h], leaky(es[(size_t)s * 4 + h] + edv[h]));
  }
  #pragma unroll
  for (int h = 0; h < 4; h++)
    #pragma unroll
    for (int off = 32; off > 0; off >>= 1)
      em[h] = fmaxf(em[h], __shfl_xor(em[h], off));

  float den[4] = {0.f, 0.f, 0.f, 0.f};
  for (int i = beg + lane; i < end; i += 64) {
    int s = ssrc[i];
    #pragma unroll
    for (int h = 0; h < 4; h++)
      den[h] += __expf(leaky(es[(size_t)s * 4 + h] + edv[h]) - em[h]);
  }
  #pragma unroll
  for (int h = 0; h < 4; h++) {
    #pragma unroll
    for (int off = 32; off > 0; off >>= 1) den[h] += __shfl_xor(den[h], off);
    den[h] = 1.f / den[h];
  }

  int h = lane >> 4;  // cols lane*4..+3 all in head lane/16
  float emh = sel4(em, h), dnh = sel4(den, h), edh = sel4(edv, h);
  float a0 = 0.f, a1 = 0.f, a2 = 0.f, a3 = 0.f;
  for (int i = beg; i < end; i++) {
    int s = ssrc[i];
    float a = __expf(leaky(es[(size_t)s * 4 + h] + edh) - emh) * dnh;
    u16x4 f = *(const u16x4*)(hfeat + (size_t)s * 256 + lane * 4);
    a0 += a * bf2f(f[0]); a1 += a * bf2f(f[1]);
    a2 += a * bf2f(f[2]); a3 += a * bf2f(f[3]);
  }
  float4* xp = (float4*)(x0 + (size_t)node * 256 + lane * 4);
  float4 cur = *xp;
  cur.x += a0; cur.y += a1; cur.z += a2; cur.w += a3;
  *xp = cur;
}

// ---------------- layer 2 fused: 5 skinny GEMMs + scores ----------------
__global__ __launch_bounds__(256) void layer2_fused_k(
    const unsigned short* __restrict__ xa,  // [NN][256] bf16
    const float* __restrict__ skW,          // [256][2]
    const float* __restrict__ W,            // [4][256][2]
    const float* __restrict__ As2,          // [4][2]
    const float* __restrict__ Ad2,          // [4][2]
    const float* __restrict__ skbe,         // [2]
    float* __restrict__ x02,                // [NN][2]
    float* __restrict__ hf2,                // [4][NN][2]
    float* __restrict__ es2,                // [4][NN]
    float* __restrict__ ed2) {              // [4][NN]
  __shared__ float wsk[256][2];
  __shared__ float wcl[4][256][2];
  int t = threadIdx.x;
  wsk[t][0] = skW[t * 2];
  wsk[t][1] = skW[t * 2 + 1];
  #pragma unroll
  for (int j = 0; j < 4; j++) {
    wcl[j][t][0] = W[j * 512 + t * 2];
    wcl[j][t][1] = W[j * 512 + t * 2 + 1];
  }
  __syncthreads();
  int node = blockIdx.x * 256 + t;
  if (node >= NN) return;
  const unsigned short* row = xa + (size_t)node * 256;
  float s0 = 0.f, s1 = 0.f;
  float h[4][2] = {};
  for (int k = 0; k < 256; k += 4) {
    u16x4 xr = *(const u16x4*)(row + k);
    #pragma unroll
    for (int q = 0; q < 4; q++) {
      float xv = bf2f(xr[q]);
      s0 += xv * wsk[k + q][0];
      s1 += xv * wsk[k + q][1];
      #pragma unroll
      for (int j = 0; j < 4; j++) {
        h[j][0] += xv * wcl[j][k + q][0];
        h[j][1] += xv * wcl[j][k + q][1];
      }
    }
  }
  x02[(size_t)node * 2]     = s0 + skbe[0];
  x02[(size_t)node * 2 + 1] = s1 + skbe[1];
  #pragma unroll
  for (int j = 0; j < 4; j++) {
    hf2[(size_t)j * NN * 2 + node * 2]     = h[j][0];
    hf2[(size_t)j * NN * 2 + node * 2 + 1] = h[j][1];
    es2[(size_t)j * NN + node] = h[j][0] * As2[j * 2] + h[j][1] * As2[j * 2 + 1];
    ed2[(size_t)j * NN + node] = h[j][0] * Ad2[j * 2] + h[j][1] * Ad2[j * 2 + 1];
  }
}

// ---------------- aggregate H=1, D=2 (f32 hfeat) ----------------
__global__ void gat_agg2_k(const float* __restrict__ hfeat,
                           const float* __restrict__ es, const float* __restrict__ ed,
                           const int* __restrict__ rs, const int* __restrict__ ssrc,
                           float* __restrict__ x0, int cls) {
  int node = blockIdx.x;
  int lane = threadIdx.x;
  int beg = rs[node * 4 + cls];
  int end = rs[node * 4 + cls + 1];
  if (beg == end) return;
  float edv = ed[node];
  float em = -1e30f;
  for (int i = beg + lane; i < end; i += 64)
    em = fmaxf(em, leaky(es[ssrc[i]] + edv));
  #pragma unroll
  for (int off = 32; off > 0; off >>= 1) em = fmaxf(em, __shfl_xor(em, off));
  float den = 0.f;
  for (int i = beg + lane; i < end; i += 64)
    den += __expf(leaky(es[ssrc[i]] + edv) - em);
  #pragma unroll
  for (int off = 32; off > 0; off >>= 1) den += __shfl_xor(den, off);
  float inv = 1.f / den;
  float a0 = 0.f, a1 = 0.f;
  for (int i = beg + lane; i < end; i += 64) {
    int s = ssrc[i];
    float a = __expf(leaky(es[s] + edv) - em) * inv;
    a0 += a * hfeat[(size_t)s * 2];
    a1 += a * hfeat[(size_t)s * 2 + 1];
  }
  #pragma unroll
  for (int off = 32; off > 0; off >>= 1) {
    a0 += __shfl_xor(a0, off);
    a1 += __shfl_xor(a1, off);
  }
  if (lane == 0) {
    x0[(size_t)node * 2]     += a0;
    x0[(size_t)node * 2 + 1] += a1;
  }
}

__global__ void relu_k(const float* __restrict__ in, float* __restrict__ out, int n) {
  for (int i = blockIdx.x * 256 + threadIdx.x; i < n; i += gridDim.x * 256)
    out[i] = fmaxf(in[i], 0.f);
}

// ---------------- launch ----------------
extern "C" void kernel_launch(void* const* d_in, const int* in_sizes, int n_in,
                              void* d_out, int out_size, void* d_ws, size_t ws_size,
                              hipStream_t stream) {
  (void)in_sizes; (void)n_in; (void)out_size; (void)ws_size;
  const float* x_in = (const float*)d_in[0];
  const int* ei  = (const int*)d_in[1];
  const int* cls = (const int*)d_in[2];
  const float *W[3], *Asr[3], *Adr[3], *cb[3], *skW[3], *skb[3], *bng[3], *bnb[3];
  for (int i = 0; i < 3; i++) {
    int b = 3 + 8 * i;
    W[i]   = (const float*)d_in[b + 0];
    Asr[i] = (const float*)d_in[b + 1];
    Adr[i] = (const float*)d_in[b + 2];
    cb[i]  = (const float*)d_in[b + 3];
    skW[i] = (const float*)d_in[b + 4];
    skb[i] = (const float*)d_in[b + 5];
    bng[i] = (const float*)d_in[b + 6];
    bnb[i] = (const float*)d_in[b + 7];
  }
  float* out = (float*)d_out;

  char* wsp = (char*)d_ws;
  auto alloc = [&](size_t bytes) {
    char* p = wsp;
    wsp += (bytes + 255) & ~(size_t)255;
    return p;
  };
  float*          x0    = (float*)alloc((size_t)NN * 256 * 4);           // 51.2 MB
  unsigned short* xa    = (unsigned short*)alloc((size_t)NN * 256 * 2);  // 25.6 MB
  unsigned short* hfeat = (unsigned short*)alloc((size_t)NN * 256 * 2);  // 25.6 MB
  float*          hf2   = (float*)alloc((size_t)4 * NN * 2 * 4);         // 1.6 MB
  float*          esb   = (float*)alloc((size_t)NN * 4 * 4);
  float*          edb   = (float*)alloc((size_t)NN * 4 * 4);
  float*          stats = (float*)alloc(512 * 4);
  float*          scale = (float*)alloc(256 * 4);
  float*          shift = (float*)alloc(256 * 4);
  float*          skbe  = (float*)alloc(256 * 4);
  unsigned short* wt    = (unsigned short*)alloc((size_t)409600 * 2);    // 0.8 MB
  int*            counts = (int*)alloc((size_t)NN * 4 * 4);
  int*            rs     = (int*)alloc(((size_t)NN * 4 + 1) * 4);
  int*            cursor = (int*)alloc((size_t)NN * 4 * 4);
  int*            bsum   = (int*)alloc(256 * 4);
  int*            ssrc   = (int*)alloc((size_t)EE * 4);

  // ---- CSR by (dst, class) ----
  hipMemsetAsync(counts, 0, (size_t)NN * 4 * 4, stream);
  hipMemsetAsync(cursor, 0, (size_t)NN * 4 * 4, stream);
  count_edges_k<<<(EE + 255) / 256, 256, 0, stream>>>(ei, cls, counts);
  scan_local_k<<<196, 256, 0, stream>>>(counts, rs, bsum, NN * 4);
  scan_bsum_k<<<1, 256, 0, stream>>>(bsum, 196);
  scan_add_k<<<196, 256, 0, stream>>>(rs, bsum, NN * 4);
  fill_edges_k<<<(EE + 255) / 256, 256, 0, stream>>>(ei, cls, rs, cursor, ssrc);

  // ---- weights -> bf16 transposed (layers 0/1) ----
  conv_weights_k<<<1600, 256, 0, stream>>>(skW[0], W[0], skW[1], W[1], wt);

  // ---- layers 0 and 1 ----
  const float* lin = x_in;
  for (int L = 0; L < 2; L++) {
    int din = (L == 0) ? 64 : 256;
    int total = NN * din;
    hipMemsetAsync(stats, 0, 512 * 4, stream);
    bn_stats_k<<<512, 256, 0, stream>>>(lin, stats, din, total);
    bn_finalize_k<<<1, 256, 0, stream>>>(stats, bng[L], bnb[L], scale, shift, din,
                                         skb[L], cb[L], skbe, 256);
    bn_apply_bf16_k<<<2048, 256, 0, stream>>>(lin, xa, scale, shift, din - 1, total);

    const unsigned short* wsk = wt + (L ? 81920 : 0);
    dim3 gg(2, (NN + 127) / 128);  // N=256 -> 2 col blocks
    gemm_bf16_k<<<gg, 256, 0, stream>>>(xa, wsk, skbe, x0, nullptr, NN, din, 256);
    for (int j = 0; j < 4; j++) {
      const unsigned short* wj = wt + (L ? 147456 + j * 65536 : 16384 + j * 16384);
      gemm_bf16_k<<<gg, 256, 0, stream>>>(xa, wj, nullptr, nullptr, hfeat, NN, din, 256);
      attn_scores4_k<<<NN / 4, 256, 0, stream>>>(hfeat, Asr[L] + j * 256,
                                                 Adr[L] + j * 256, esb, edb);
      gat_agg4_k<<<NN, 64, 0, stream>>>(hfeat, esb, edb, rs, ssrc, x0, j);
    }
    relu_k<<<2048, 256, 0, stream>>>(x0, x0, NN * 256);
    lin = x0;
  }

  // ---- layer 2 ----
  hipMemsetAsync(stats, 0, 512 * 4, stream);
  bn_stats_k<<<512, 256, 0, stream>>>(x0, stats, 256, NN * 256);
  bn_finalize_k<<<1, 256, 0, stream>>>(stats, bng[2], bnb[2], scale, shift, 256,
                                       skb[2], cb[2], skbe, 2);
  bn_apply_bf16_k<<<2048, 256, 0, stream>>>(x0, xa, scale, shift, 255, NN * 256);
  layer2_fused_k<<<(NN + 255) / 256, 256, 0, stream>>>(xa, skW[2], W[2], Asr[2], Adr[2],
                                                       skbe, x0, hf2, esb, edb);
  for (int j = 0; j < 4; j++)
    gat_agg2_k<<<NN, 64, 0, stream>>>(hf2 + (size_t)j * NN * 2, esb + (size_t)j * NN,
                                      edb + (size_t)j * NN, rs, ssrc, x0, j);
  relu_k<<<2048, 256, 0, stream>>>(x0, out, NN * 2);
}

// Round 3
// 946.626 us; speedup vs baseline: 4.4385x; 3.4825x over previous
//
#include <hip/hip_runtime.h>
#include <cstddef>
#include <cstdint>

#define NN 50000
#define EE 800000

constexpr float BN_EPS   = 1e-5f;
constexpr float NEGSLOPE = 0.2f;

typedef short s16x8 __attribute__((ext_vector_type(8)));
typedef float f32x4 __attribute__((ext_vector_type(4)));
typedef unsigned short u16x4 __attribute__((ext_vector_type(4)));

__device__ __forceinline__ unsigned short f2bf(float f) {
  unsigned int u = __float_as_uint(f);
  unsigned int r = (u + 0x7fffu + ((u >> 16) & 1u)) >> 16;
  return (unsigned short)r;
}
__device__ __forceinline__ float bf2f(unsigned short u) {
  return __uint_as_float(((unsigned int)u) << 16);
}
__device__ __forceinline__ float leaky(float e) { return e >= 0.f ? e : NEGSLOPE * e; }
__device__ __forceinline__ float sel4(float v0, float v1, float v2, float v3, int h) {
  float r = v0;
  r = (h == 1) ? v1 : r;
  r = (h == 2) ? v2 : r;
  r = (h == 3) ? v3 : r;
  return r;
}
__device__ __forceinline__ void gl_lds16(const unsigned short* g, unsigned short* l) {
  __builtin_amdgcn_global_load_lds(
      (const __attribute__((address_space(1))) unsigned int*)(g),
      (__attribute__((address_space(3))) unsigned int*)(l), 16, 0, 0);
}

// ---------------- CSR build: group edges by (dst*4 + class) ----------------
__global__ void count_edges_k(const int* __restrict__ ei, const int* __restrict__ cls,
                              int* __restrict__ counts) {
  int e = blockIdx.x * 256 + threadIdx.x;
  if (e >= EE) return;
  int dst = ei[EE + e];
  int c   = cls[e];
  atomicAdd(&counts[dst * 4 + c], 1);
}

__global__ void scan_local_k(const int* __restrict__ counts, int* __restrict__ rs,
                             int* __restrict__ bsum, int n) {
  __shared__ int sh[256];
  int b = blockIdx.x, t = threadIdx.x;
  int base = b * 1024;
  int v[4];
  #pragma unroll
  for (int q = 0; q < 4; q++) {
    int i = base + t * 4 + q;
    v[q] = (i < n) ? counts[i] : 0;
  }
  v[1] += v[0]; v[2] += v[1]; v[3] += v[2];
  sh[t] = v[3];
  __syncthreads();
  for (int off = 1; off < 256; off <<= 1) {
    int x = (t >= off) ? sh[t - off] : 0;
    __syncthreads();
    sh[t] += x;
    __syncthreads();
  }
  int prev = (t > 0) ? sh[t - 1] : 0;
  #pragma unroll
  for (int q = 0; q < 4; q++) {
    int i = base + t * 4 + q;
    if (i < n) rs[i + 1] = prev + v[q];
  }
  if (t == 255) bsum[b] = sh[255];
}

__global__ void scan_bsum_k(int* __restrict__ bsum, int nb) {
  __shared__ int sh[256];
  int t = threadIdx.x;
  sh[t] = (t < nb) ? bsum[t] : 0;
  __syncthreads();
  for (int off = 1; off < 256; off <<= 1) {
    int x = (t >= off) ? sh[t - off] : 0;
    __syncthreads();
    sh[t] += x;
    __syncthreads();
  }
  if (t < nb) bsum[t] = (t > 0) ? sh[t - 1] : 0;
}

__global__ void scan_add_k(int* __restrict__ rs, const int* __restrict__ bsum, int n) {
  int b = blockIdx.x, t = threadIdx.x;
  int off = bsum[b];
  #pragma unroll
  for (int q = 0; q < 4; q++) {
    int i = b * 1024 + t * 4 + q;
    if (i < n) rs[i + 1] += off;
  }
  if (b == 0 && t == 0) rs[0] = 0;
}

__global__ void fill_edges_k(const int* __restrict__ ei, const int* __restrict__ cls,
                             const int* __restrict__ rs, int* __restrict__ cursor,
                             int* __restrict__ ssrc) {
  int e = blockIdx.x * 256 + threadIdx.x;
  if (e >= EE) return;
  int dst = ei[EE + e];
  int c   = cls[e];
  int bin = dst * 4 + c;
  int pos = rs[bin] + atomicAdd(&cursor[bin], 1);
  ssrc[pos] = ei[e];
}

// ---------------- BatchNorm (optionally fused ReLU on the read) ----------------
template <bool RELU>
__global__ void bn_stats_k(const float* __restrict__ x, float* __restrict__ sums,
                           int din, int total) {
  __shared__ float ls[512];
  int t = threadIdx.x;
  for (int i = t; i < 2 * din; i += 256) ls[i] = 0.f;
  __syncthreads();
  int c = (blockIdx.x * 256 + t) % din;
  float s = 0.f, ss = 0.f;
  for (int idx = blockIdx.x * 256 + t; idx < total; idx += gridDim.x * 256) {
    float v = x[idx];
    if (RELU) v = fmaxf(v, 0.f);
    s += v; ss += v * v;
  }
  atomicAdd(&ls[c], s);
  atomicAdd(&ls[din + c], ss);
  __syncthreads();
  for (int i = t; i < 2 * din; i += 256) atomicAdd(&sums[i], ls[i]);
}

__global__ void bn_finalize_k(const float* __restrict__ sums, const float* __restrict__ g,
                              const float* __restrict__ b, float* __restrict__ scale,
                              float* __restrict__ shift, int din,
                              const float* __restrict__ skb, const float* __restrict__ cb,
                              float* __restrict__ skbe, int hd) {
  int i = threadIdx.x;
  if (i < din) {
    float m  = sums[i] / (float)NN;
    float v  = sums[din + i] / (float)NN - m * m;
    float r  = rsqrtf(v + BN_EPS);
    float sc = r * g[i];
    scale[i] = sc;
    shift[i] = b[i] - m * sc;
  }
  if (i < hd) {
    float acc = skb[i];
    #pragma unroll
    for (int j = 0; j < 4; j++) acc += cb[j * hd + i];
    skbe[i] = acc;
  }
}

template <bool RELU>
__global__ void bn_apply_bf16_k(const float* __restrict__ x, unsigned short* __restrict__ xn,
                                const float* __restrict__ scale, const float* __restrict__ shift,
                                int dmask, int total) {
  for (int i = blockIdx.x * 256 + threadIdx.x; i < total; i += gridDim.x * 256) {
    int c = i & dmask;
    float v = x[i];
    if (RELU) v = fmaxf(v, 0.f);
    xn[i] = f2bf(v * scale[c] + shift[c]);
  }
}

// ---------------- weight convert+transpose to bf16 (layers 0/1) ----------------
__global__ void conv_weights_k(const float* __restrict__ skW0, const float* __restrict__ W0,
                               const float* __restrict__ skW1, const float* __restrict__ W1,
                               unsigned short* __restrict__ wt) {
  int o = blockIdx.x * 256 + threadIdx.x;
  if (o >= 409600) return;
  float v;
  if (o < 16384) {                       // skW0^T [256][64]
    int n = o >> 6, k = o & 63;
    v = skW0[k * 256 + n];
  } else if (o < 81920) {                // W0^T [4][256][64]
    int w = o - 16384; int j = w >> 14; w &= 16383;
    int n = w >> 6, k = w & 63;
    v = W0[j * 16384 + k * 256 + n];
  } else if (o < 147456) {               // skW1^T [256][256]
    int w = o - 81920;
    int n = w >> 8, k = w & 255;
    v = skW1[k * 256 + n];
  } else {                               // W1^T [4][256][256]
    int w = o - 147456; int j = w >> 16; w &= 65535;
    int n = w >> 8, k = w & 255;
    v = W1[j * 65536 + k * 256 + n];
  }
  wt[o] = f2bf(v);
}

// ---------------- bf16 MFMA GEMM (batched over blockIdx.z) ----------------
__global__ __launch_bounds__(256) void gemm_bf16_k(
    const unsigned short* __restrict__ A,   // [M,K] bf16
    const unsigned short* __restrict__ Bt,  // [z][N,K] bf16
    const float* __restrict__ bias,         // [N] or null
    float* __restrict__ Cf,                 // f32 out (or null)
    unsigned short* __restrict__ Cb,        // bf16 out (or null)
    int M, int K, int N, int strideBt, long long strideC) {
  __shared__ unsigned short As[128 * 32];
  __shared__ unsigned short Bs[128 * 32];
  int z = blockIdx.z;
  Bt += (size_t)z * strideBt;
  int tid  = threadIdx.x;
  int lane = tid & 63;
  int w    = tid >> 6;
  int lm = lane & 15, lq = lane >> 4;
  int row0 = blockIdx.y * 128, col0 = blockIdx.x * 128;
  int wr = (w >> 1) * 64, wc = (w & 1) * 64;
  f32x4 acc[4][4];
  #pragma unroll
  for (int i = 0; i < 4; i++)
    #pragma unroll
    for (int j = 0; j < 4; j++) acc[i][j] = {0.f, 0.f, 0.f, 0.f};
  int ldsbase = (tid & ~63) * 16;

  for (int k0 = 0; k0 < K; k0 += 32) {
    #pragma unroll
    for (int r = 0; r < 2; r++) {
      int ia = r * 256 + tid;
      int arow = row0 + (ia >> 2);
      if (arow >= M) arow = M - 1;
      const unsigned short* ga = A + (size_t)arow * K + k0 + (ia & 3) * 8;
      gl_lds16(ga, (unsigned short*)((char*)As + r * 4096 + ldsbase));
      int bcol = col0 + (ia >> 2);
      const unsigned short* gb = Bt + (size_t)bcol * K + k0 + (ia & 3) * 8;
      gl_lds16(gb, (unsigned short*)((char*)Bs + r * 4096 + ldsbase));
    }
    __syncthreads();
    s16x8 af[4], bfr[4];
    #pragma unroll
    for (int i = 0; i < 4; i++)
      af[i] = *(const s16x8*)&As[(wr + i * 16 + lm) * 32 + lq * 8];
    #pragma unroll
    for (int j = 0; j < 4; j++)
      bfr[j] = *(const s16x8*)&Bs[(wc + j * 16 + lm) * 32 + lq * 8];
    #pragma unroll
    for (int i = 0; i < 4; i++)
      #pragma unroll
      for (int j = 0; j < 4; j++)
        acc[i][j] = __builtin_amdgcn_mfma_f32_16x16x32_bf16(af[i], bfr[j], acc[i][j], 0, 0, 0);
    __syncthreads();
  }

  #pragma unroll
  for (int i = 0; i < 4; i++) {
    #pragma unroll
    for (int j = 0; j < 4; j++) {
      int c = col0 + wc + j * 16 + lm;
      #pragma unroll
      for (int rg = 0; rg < 4; rg++) {
        int r = row0 + wr + i * 16 + lq * 4 + rg;
        if (r < M) {
          float v = acc[i][j][rg];
          if (Cf) {
            if (bias) v += bias[c];
            Cf[(size_t)r * N + c] = v;
          } else {
            Cb[(size_t)z * strideC + (size_t)r * N + c] = f2bf(v);
          }
        }
      }
    }
  }
}

// ---------------- attention scores, all 4 classes in one dispatch ----------------
__global__ void attn_scores4_all_k(const unsigned short* __restrict__ hfeat4,
                                   const float* __restrict__ asrc,  // [4][4][64]
                                   const float* __restrict__ adst,
                                   float* __restrict__ es4,         // [4][NN][4]
                                   float* __restrict__ ed4) {
  int node = blockIdx.x;
  int j    = threadIdx.x >> 6;
  int lane = threadIdx.x & 63;
  const unsigned short* hrow = hfeat4 + ((size_t)j * NN + node) * 256;
  float esr[4], edr[4];
  #pragma unroll
  for (int h = 0; h < 4; h++) {
    float v  = bf2f(hrow[h * 64 + lane]);
    float ps = v * asrc[j * 256 + h * 64 + lane];
    float pd = v * adst[j * 256 + h * 64 + lane];
    #pragma unroll
    for (int off = 32; off > 0; off >>= 1) {
      ps += __shfl_xor(ps, off);
      pd += __shfl_xor(pd, off);
    }
    esr[h] = ps; edr[h] = pd;
  }
  if (lane == 0) {
    *(float4*)(es4 + ((size_t)j * NN + node) * 4) = make_float4(esr[0], esr[1], esr[2], esr[3]);
    *(float4*)(ed4 + ((size_t)j * NN + node) * 4) = make_float4(edr[0], edr[1], edr[2], edr[3]);
  }
}

// ---------------- fused aggregate: all 4 classes, single pass, one wave/node ----
__global__ __launch_bounds__(256) void gat_agg4_fused_k(
    const unsigned short* __restrict__ hfeat4,  // [4][NN][256] bf16
    const float* __restrict__ es4,              // [4][NN][4]
    const float* __restrict__ ed4,              // [4][NN][4]
    const int* __restrict__ rs, const int* __restrict__ ssrc,
    float* __restrict__ x0) {                   // [NN][256] += msg
  int node = blockIdx.x * 4 + (threadIdx.x >> 6);
  int lane = threadIdx.x & 63;
  if (node >= NN) return;
  int r0 = rs[node * 4 + 0], r1 = rs[node * 4 + 1], r2 = rs[node * 4 + 2],
      r3 = rs[node * 4 + 3], r4 = rs[node * 4 + 4];
  if (r0 == r4) return;  // no edges in any class: contribution 0
  int h = lane >> 4;     // this lane's head (cols lane*4..+3)

  float acc[4][4];
  float den[4];
  #pragma unroll
  for (int j = 0; j < 4; j++) {
    den[j] = 0.f;
    #pragma unroll
    for (int q = 0; q < 4; q++) acc[j][q] = 0.f;
  }

  #pragma unroll
  for (int j = 0; j < 4; j++) {
    int beg = (j == 0) ? r0 : (j == 1) ? r1 : (j == 2) ? r2 : r3;
    int end = (j == 0) ? r1 : (j == 1) ? r2 : (j == 2) ? r3 : r4;
    if (beg == end) continue;
    const float4 edv = *(const float4*)(ed4 + ((size_t)j * NN + node) * 4);
    const unsigned short* hfj = hfeat4 + (size_t)j * NN * 256;
    const float* esj = es4 + (size_t)j * NN * 4;
    for (int base = beg; base < end; base += 64) {
      int idx = base + lane;
      int s = -1;
      float w0 = 0.f, w1 = 0.f, w2 = 0.f, w3 = 0.f;
      if (idx < end) {
        s = ssrc[idx];
        float4 ev = *(const float4*)(esj + (size_t)s * 4);
        w0 = __expf(leaky(ev.x + edv.x));
        w1 = __expf(leaky(ev.y + edv.y));
        w2 = __expf(leaky(ev.z + edv.z));
        w3 = __expf(leaky(ev.w + edv.w));
      }
      int n_e = min(64, end - base);
      #pragma unroll 2
      for (int i = 0; i < n_e; i++) {
        int si   = __shfl(s, i);
        float b0 = __shfl(w0, i), b1 = __shfl(w1, i),
              b2 = __shfl(w2, i), b3 = __shfl(w3, i);
        float wh = sel4(b0, b1, b2, b3, h);
        u16x4 f = *(const u16x4*)(hfj + (size_t)si * 256 + lane * 4);
        acc[j][0] += wh * bf2f(f[0]);
        acc[j][1] += wh * bf2f(f[1]);
        acc[j][2] += wh * bf2f(f[2]);
        acc[j][3] += wh * bf2f(f[3]);
        den[j] += wh;
      }
    }
  }

  float4* xp = (float4*)(x0 + (size_t)node * 256 + lane * 4);
  float4 cur = *xp;
  #pragma unroll
  for (int j = 0; j < 4; j++) {
    if (den[j] > 0.f) {
      float inv = 1.f / den[j];
      cur.x += acc[j][0] * inv;
      cur.y += acc[j][1] * inv;
      cur.z += acc[j][2] * inv;
      cur.w += acc[j][3] * inv;
    }
  }
  *xp = cur;
}

// ---------------- layer 2 fused: 5 skinny GEMMs + scores ----------------
__global__ __launch_bounds__(256) void layer2_fused_k(
    const unsigned short* __restrict__ xa,  // [NN][256] bf16
    const float* __restrict__ skW,          // [256][2]
    const float* __restrict__ W,            // [4][256][2]
    const float* __restrict__ As2,          // [4][2]
    const float* __restrict__ Ad2,          // [4][2]
    const float* __restrict__ skbe,         // [2]
    float* __restrict__ x02,                // [NN][2]
    float* __restrict__ hf2,                // [4][NN][2]
    float* __restrict__ es2,                // [4][NN]
    float* __restrict__ ed2) {              // [4][NN]
  __shared__ float wsk[256][2];
  __shared__ float wcl[4][256][2];
  int t = threadIdx.x;
  wsk[t][0] = skW[t * 2];
  wsk[t][1] = skW[t * 2 + 1];
  #pragma unroll
  for (int j = 0; j < 4; j++) {
    wcl[j][t][0] = W[j * 512 + t * 2];
    wcl[j][t][1] = W[j * 512 + t * 2 + 1];
  }
  __syncthreads();
  int node = blockIdx.x * 256 + t;
  if (node >= NN) return;
  const unsigned short* row = xa + (size_t)node * 256;
  float s0 = 0.f, s1 = 0.f;
  float h[4][2] = {};
  for (int k = 0; k < 256; k += 4) {
    u16x4 xr = *(const u16x4*)(row + k);
    #pragma unroll
    for (int q = 0; q < 4; q++) {
      float xv = bf2f(xr[q]);
      s0 += xv * wsk[k + q][0];
      s1 += xv * wsk[k + q][1];
      #pragma unroll
      for (int j = 0; j < 4; j++) {
        h[j][0] += xv * wcl[j][k + q][0];
        h[j][1] += xv * wcl[j][k + q][1];
      }
    }
  }
  x02[(size_t)node * 2]     = s0 + skbe[0];
  x02[(size_t)node * 2 + 1] = s1 + skbe[1];
  #pragma unroll
  for (int j = 0; j < 4; j++) {
    hf2[((size_t)j * NN + node) * 2]     = h[j][0];
    hf2[((size_t)j * NN + node) * 2 + 1] = h[j][1];
    es2[(size_t)j * NN + node] = h[j][0] * As2[j * 2] + h[j][1] * As2[j * 2 + 1];
    ed2[(size_t)j * NN + node] = h[j][0] * Ad2[j * 2] + h[j][1] * Ad2[j * 2 + 1];
  }
}

// ---------------- fused aggregate for layer 2 (H=1, D=2) ----------------
__global__ __launch_bounds__(256) void gat_agg2_fused_k(
    const float* __restrict__ hf2,  // [4][NN][2]
    const float* __restrict__ es2,  // [4][NN]
    const float* __restrict__ ed2,  // [4][NN]
    const int* __restrict__ rs, const int* __restrict__ ssrc,
    float* __restrict__ x0) {       // [NN][2]
  int node = blockIdx.x * 4 + (threadIdx.x >> 6);
  int lane = threadIdx.x & 63;
  if (node >= NN) return;
  float add0 = 0.f, add1 = 0.f;
  #pragma unroll
  for (int j = 0; j < 4; j++) {
    int beg = rs[node * 4 + j], end = rs[node * 4 + j + 1];
    if (beg == end) continue;
    float edv = ed2[(size_t)j * NN + node];
    float nw = 0.f, n0 = 0.f, n1 = 0.f;
    for (int idx = beg + lane; idx < end; idx += 64) {
      int s = ssrc[idx];
      float w = __expf(leaky(es2[(size_t)j * NN + s] + edv));
      float2 f = *(const float2*)(hf2 + ((size_t)j * NN + s) * 2);
      nw += w; n0 += w * f.x; n1 += w * f.y;
    }
    #pragma unroll
    for (int off = 32; off > 0; off >>= 1) {
      nw += __shfl_xor(nw, off);
      n0 += __shfl_xor(n0, off);
      n1 += __shfl_xor(n1, off);
    }
    float inv = 1.f / nw;
    add0 += n0 * inv;
    add1 += n1 * inv;
  }
  if (lane == 0) {
    x0[(size_t)node * 2]     += add0;
    x0[(size_t)node * 2 + 1] += add1;
  }
}

__global__ void relu_k(const float* __restrict__ in, float* __restrict__ out, int n) {
  for (int i = blockIdx.x * 256 + threadIdx.x; i < n; i += gridDim.x * 256)
    out[i] = fmaxf(in[i], 0.f);
}

// ---------------- launch ----------------
extern "C" void kernel_launch(void* const* d_in, const int* in_sizes, int n_in,
                              void* d_out, int out_size, void* d_ws, size_t ws_size,
                              hipStream_t stream) {
  (void)in_sizes; (void)n_in; (void)out_size; (void)ws_size;
  const float* x_in = (const float*)d_in[0];
  const int* ei  = (const int*)d_in[1];
  const int* cls = (const int*)d_in[2];
  const float *W[3], *Asr[3], *Adr[3], *cb[3], *skW[3], *skb[3], *bng[3], *bnb[3];
  for (int i = 0; i < 3; i++) {
    int b = 3 + 8 * i;
    W[i]   = (const float*)d_in[b + 0];
    Asr[i] = (const float*)d_in[b + 1];
    Adr[i] = (const float*)d_in[b + 2];
    cb[i]  = (const float*)d_in[b + 3];
    skW[i] = (const float*)d_in[b + 4];
    skb[i] = (const float*)d_in[b + 5];
    bng[i] = (const float*)d_in[b + 6];
    bnb[i] = (const float*)d_in[b + 7];
  }
  float* out = (float*)d_out;

  char* wsp = (char*)d_ws;
  auto alloc = [&](size_t bytes) {
    char* p = wsp;
    wsp += (bytes + 255) & ~(size_t)255;
    return p;
  };
  float*          x0     = (float*)alloc((size_t)NN * 256 * 4);              // 51.2 MB
  unsigned short* xa     = (unsigned short*)alloc((size_t)NN * 256 * 2);     // 25.6 MB
  unsigned short* hfeat4 = (unsigned short*)alloc((size_t)4 * NN * 256 * 2); // 102.4 MB
  float*          hf2    = (float*)alloc((size_t)4 * NN * 2 * 4);            // 1.6 MB
  float*          es4    = (float*)alloc((size_t)4 * NN * 4 * 4);            // 3.2 MB
  float*          ed4    = (float*)alloc((size_t)4 * NN * 4 * 4);            // 3.2 MB
  float*          stats  = (float*)alloc(512 * 4);
  float*          scale  = (float*)alloc(256 * 4);
  float*          shift  = (float*)alloc(256 * 4);
  float*          skbe   = (float*)alloc(256 * 4);
  unsigned short* wt     = (unsigned short*)alloc((size_t)409600 * 2);
  int*            counts = (int*)alloc((size_t)NN * 4 * 4);
  int*            rs     = (int*)alloc(((size_t)NN * 4 + 1) * 4);
  int*            cursor = (int*)alloc((size_t)NN * 4 * 4);
  int*            bsum   = (int*)alloc(256 * 4);
  int*            ssrc   = (int*)alloc((size_t)EE * 4);

  // ---- CSR by (dst, class) ----
  hipMemsetAsync(counts, 0, (size_t)NN * 4 * 4, stream);
  hipMemsetAsync(cursor, 0, (size_t)NN * 4 * 4, stream);
  count_edges_k<<<(EE + 255) / 256, 256, 0, stream>>>(ei, cls, counts);
  scan_local_k<<<196, 256, 0, stream>>>(counts, rs, bsum, NN * 4);
  scan_bsum_k<<<1, 256, 0, stream>>>(bsum, 196);
  scan_add_k<<<196, 256, 0, stream>>>(rs, bsum, NN * 4);
  fill_edges_k<<<(EE + 255) / 256, 256, 0, stream>>>(ei, cls, rs, cursor, ssrc);

  // ---- weights -> bf16 transposed (layers 0/1) ----
  conv_weights_k<<<1600, 256, 0, stream>>>(skW[0], W[0], skW[1], W[1], wt);

  // ---- layers 0 and 1 ----
  for (int L = 0; L < 2; L++) {
    int din = (L == 0) ? 64 : 256;
    int total = NN * din;
    const float* lin = (L == 0) ? x_in : x0;
    hipMemsetAsync(stats, 0, 512 * 4, stream);
    if (L == 0) {
      bn_stats_k<false><<<512, 256, 0, stream>>>(lin, stats, din, total);
    } else {
      bn_stats_k<true><<<512, 256, 0, stream>>>(lin, stats, din, total);
    }
    bn_finalize_k<<<1, 256, 0, stream>>>(stats, bng[L], bnb[L], scale, shift, din,
                                         skb[L], cb[L], skbe, 256);
    if (L == 0) {
      bn_apply_bf16_k<false><<<2048, 256, 0, stream>>>(lin, xa, scale, shift, din - 1, total);
    } else {
      bn_apply_bf16_k<true><<<2048, 256, 0, stream>>>(lin, xa, scale, shift, din - 1, total);
    }

    const unsigned short* wsk = wt + (L ? 81920 : 0);
    dim3 ggs(2, (NN + 127) / 128, 1);
    gemm_bf16_k<<<ggs, 256, 0, stream>>>(xa, wsk, skbe, x0, nullptr, NN, din, 256, 0, 0);
    const unsigned short* wcv = wt + (L ? 147456 : 16384);
    int sB = L ? 65536 : 16384;
    dim3 ggc(2, (NN + 127) / 128, 4);
    gemm_bf16_k<<<ggc, 256, 0, stream>>>(xa, wcv, nullptr, nullptr, hfeat4, NN, din, 256,
                                         sB, (long long)NN * 256);
    attn_scores4_all_k<<<NN, 256, 0, stream>>>(hfeat4, Asr[L], Adr[L], es4, ed4);
    gat_agg4_fused_k<<<(NN + 3) / 4, 256, 0, stream>>>(hfeat4, es4, ed4, rs, ssrc, x0);
  }

  // ---- layer 2 ----
  hipMemsetAsync(stats, 0, 512 * 4, stream);
  bn_stats_k<true><<<512, 256, 0, stream>>>(x0, stats, 256, NN * 256);
  bn_finalize_k<<<1, 256, 0, stream>>>(stats, bng[2], bnb[2], scale, shift, 256,
                                       skb[2], cb[2], skbe, 2);
  bn_apply_bf16_k<true><<<2048, 256, 0, stream>>>(x0, xa, scale, shift, 255, NN * 256);
  layer2_fused_k<<<(NN + 255) / 256, 256, 0, stream>>>(xa, skW[2], W[2], Asr[2], Adr[2],
                                                       skbe, x0, hf2, es4, ed4);
  gat_agg2_fused_k<<<(NN + 3) / 4, 256, 0, stream>>>(hf2, es4, ed4, rs, ssrc, x0);
  relu_k<<<64, 256, 0, stream>>>(x0, out, NN * 2);
}